// Round 1
// baseline (104.230 us; speedup 1.0000x reference)
//
#include <hip/hip_runtime.h>
#include <hip/hip_bf16.h>

#define N_TOK 4096
#define DIM   1024
#define H2V   4096
#define HV    2048
#define NE    8
#define BM    128
#define BN    64
#define BK    64
#define NTHR  256
#define ROW_TILES (N_TOK / BM)   // 32 worst-case row tiles per expert

typedef __attribute__((ext_vector_type(4))) float  f32x4;
typedef __attribute__((ext_vector_type(2))) float  f32x2;
typedef __attribute__((ext_vector_type(8))) short  s16x8;

__device__ __forceinline__ unsigned short f2bf(float f) {
    __hip_bfloat16 h = __float2bfloat16(f);
    union { __hip_bfloat16 h; unsigned short u; } v;
    v.h = h;
    return v.u;
}

__global__ void k_init(int* __restrict__ counts) {
    if (threadIdx.x < NE) counts[threadIdx.x] = 0;
}

__global__ void k_scatter(const int* __restrict__ idx, int* __restrict__ counts,
                          unsigned short* __restrict__ slots) {
    int n = blockIdx.x * blockDim.x + threadIdx.x;
    if (n < N_TOK) {
        int e = idx[n];
        int p = atomicAdd(&counts[e], 1);   // device-scope: cross-XCD safe
        slots[e * N_TOK + p] = (unsigned short)n;
    }
}

__global__ __launch_bounds__(NTHR, 2) void k_gemm(
        const float* __restrict__ X, const float* __restrict__ W,
        const int* __restrict__ counts, const unsigned short* __restrict__ slots,
        float* __restrict__ out) {
    const int ct = blockIdx.x;          // col tile: out cols [ct*64, ct*64+64)
    const int e  = blockIdx.y >> 5;     // expert
    const int rt = blockIdx.y & 31;     // row-tile slot within expert
    const int cnt = counts[e];
    const int tbase = rt * BM;
    if (tbase >= cnt) return;           // empty slot
    const unsigned short* ids = slots + e * N_TOK;

    // As: [row][k] bf16, 128B rows, granule-XOR swizzle key (row&7)
    // Bs: [col][k] bf16 (transposed W), swizzle key ((col>>1)&7); cols 0..63 = gate, 64..127 = up
    __shared__ unsigned short As[BM * BK];
    __shared__ unsigned short Bs[2 * BN * BK];

    const int t    = threadIdx.x;
    const int lane = t & 63;
    const int wid  = t >> 6;
    const int wm   = wid >> 1;          // wave row 0..1 (64 rows each)
    const int wn   = wid & 1;           // wave col 0..1 (32 cols each)
    const int l16  = lane & 15;
    const int g16  = lane >> 4;

    const float* Wb = W + (size_t)e * ((size_t)DIM * H2V);

    // ---- A staging geometry (constant over k-loop): thread stages 4x (row, 8k) ----
    const float* a_src[4];
    int a_row[4], a_q0[4];
#pragma unroll
    for (int p = 0; p < 4; ++p) {
        int pp = p * NTHR + t;
        a_row[p] = pp >> 3;             // 0..127
        a_q0[p]  = pp & 7;              // k-granule 0..7
        int slot = tbase + a_row[p];
        int tok  = ids[min(slot, cnt - 1)];  // clamp: result rows >= cnt are discarded
        a_src[p] = X + (size_t)tok * DIM + a_q0[p] * 8;
    }
    // ---- B staging geometry: thread stages 2x (2 cols x 8 k) micro-tiles ----
    const float* b_src[2];
    int b_c0[2], b_ko[2];
#pragma unroll
    for (int p = 0; p < 2; ++p) {
        int m2 = p * NTHR + t;          // 0..511
        int cp = m2 & 63;               // col pair
        int ko = m2 >> 6;               // k-octet 0..7
        int c0 = cp * 2;                // local col 0..126
        int gc = ct * BN + (c0 & 63) + (c0 >> 6) * HV;  // gate cols then +2048 up cols
        b_src[p] = Wb + (size_t)(ko * 8) * H2V + gc;
        b_c0[p] = c0;
        b_ko[p] = ko;
    }

    f32x4 acc[2][4][2];
    const f32x4 zero = {0.f, 0.f, 0.f, 0.f};
#pragma unroll
    for (int g = 0; g < 2; ++g)
#pragma unroll
        for (int m = 0; m < 4; ++m)
#pragma unroll
            for (int n = 0; n < 2; ++n)
                acc[g][m][n] = zero;

    for (int ks = 0; ks < DIM / BK; ++ks) {
        const int kbase = ks * BK;
        // issue global loads early (overlap previous MFMA phase)
        f32x4 av[4][2];
#pragma unroll
        for (int p = 0; p < 4; ++p) {
            const float* s = a_src[p] + kbase;
            av[p][0] = *(const f32x4*)(s);
            av[p][1] = *(const f32x4*)(s + 4);
        }
        f32x2 bv[2][8];
#pragma unroll
        for (int p = 0; p < 2; ++p) {
            const float* s = b_src[p] + (size_t)kbase * H2V;
#pragma unroll
            for (int i = 0; i < 8; ++i)
                bv[p][i] = *(const f32x2*)(s + (size_t)i * H2V);
        }
        __syncthreads();   // previous iteration's frag reads done
#pragma unroll
        for (int p = 0; p < 4; ++p) {
            int row = a_row[p], q0 = a_q0[p];
            unsigned short tmp[8];
#pragma unroll
            for (int i = 0; i < 4; ++i) tmp[i]     = f2bf(av[p][0][i]);
#pragma unroll
            for (int i = 0; i < 4; ++i) tmp[4 + i] = f2bf(av[p][1][i]);
            *(s16x8*)((char*)As + row * (BK * 2) + ((q0 ^ (row & 7)) << 4)) =
                *(const s16x8*)tmp;
        }
#pragma unroll
        for (int p = 0; p < 2; ++p) {
            int ko = b_ko[p];
#pragma unroll
            for (int j = 0; j < 2; ++j) {
                int c = b_c0[p] + j;
                unsigned short tmp[8];
#pragma unroll
                for (int i = 0; i < 8; ++i) tmp[i] = f2bf(bv[p][i][j]);
                *(s16x8*)((char*)Bs + c * (BK * 2) + ((ko ^ ((c >> 1) & 7)) << 4)) =
                    *(const s16x8*)tmp;
            }
        }
        __syncthreads();   // staging visible
#pragma unroll
        for (int kk = 0; kk < 2; ++kk) {
            s16x8 af[4], bfr[2][2];
            const int gran = kk * 4 + g16;
#pragma unroll
            for (int m = 0; m < 4; ++m) {
                int row = wm * 64 + m * 16 + l16;
                af[m] = *(const s16x8*)((const char*)As + row * (BK * 2) +
                                        ((gran ^ (row & 7)) << 4));
            }
#pragma unroll
            for (int g = 0; g < 2; ++g)
#pragma unroll
                for (int n = 0; n < 2; ++n) {
                    int c = g * BN + wn * 32 + n * 16 + l16;
                    bfr[g][n] = *(const s16x8*)((const char*)Bs + c * (BK * 2) +
                                                ((gran ^ ((c >> 1) & 7)) << 4));
                }
#pragma unroll
            for (int g = 0; g < 2; ++g)
#pragma unroll
                for (int m = 0; m < 4; ++m)
#pragma unroll
                    for (int n = 0; n < 2; ++n)
                        acc[g][m][n] = __builtin_amdgcn_mfma_f32_16x16x32_bf16(
                            af[m], bfr[g][n], acc[g][m][n], 0, 0, 0);
        }
    }

    // epilogue: silu(gate) * up, scatter rows back to token ids
#pragma unroll
    for (int m = 0; m < 4; ++m) {
#pragma unroll
        for (int r = 0; r < 4; ++r) {
            int rowt = wm * 64 + m * 16 + g16 * 4 + r;   // C/D: row=(lane>>4)*4+r
            int slot = tbase + rowt;
            if (slot < cnt) {
                int tok = ids[slot];
#pragma unroll
                for (int n = 0; n < 2; ++n) {
                    int col = ct * BN + wn * 32 + n * 16 + l16;  // C/D: col=lane&15
                    float a = acc[0][m][n][r];
                    float b = acc[1][m][n][r];
                    float sg = a / (1.0f + __expf(-a));
                    out[(size_t)tok * HV + col] = sg * b;
                }
            }
        }
    }
}

extern "C" void kernel_launch(void* const* d_in, const int* in_sizes, int n_in,
                              void* d_out, int out_size, void* d_ws, size_t ws_size,
                              hipStream_t stream) {
    const float* X  = (const float*)d_in[0];
    const float* W  = (const float*)d_in[1];
    const int* idx  = (const int*)d_in[2];
    float* out      = (float*)d_out;

    int* counts = (int*)d_ws;                                     // 8 ints
    unsigned short* slots = (unsigned short*)((char*)d_ws + 64);  // E*N u16 = 64 KiB

    k_init<<<1, 64, 0, stream>>>(counts);
    k_scatter<<<N_TOK / 256, 256, 0, stream>>>(idx, counts, slots);
    dim3 grid(HV / BN, NE * ROW_TILES);
    k_gemm<<<grid, NTHR, 0, stream>>>(X, W, counts, slots, out);
}